// Round 7
// baseline (705.229 us; speedup 1.0000x reference)
//
#include <hip/hip_runtime.h>

// LSTMForecaster: B=4096, T=512, D=1, H=64, 2 layers + FC(64->1).
// R7: complementary phase scheduling (2 barriers/step, anti-phased wave roles).
//   R6 post-mortem: MfmaUtil 47% + VALUBusy 59% = 106%, step = SUM of pipes --
//   the single barrier phase-locks all waves (all do MFMA burst, then all do
//   VALU burst). Fix: L1 lags 2 steps; per interval i:
//     Phase A: L0 cells(i-1) [VALU] + write h0(i-1)  ||  L1 gates(i-2) MFMA
//     --- mid barrier ---
//     Phase B: L0 gates(i) MFMA (reads fresh h0(i-1)) ||  L1 cells(i-2) [VALU]
//     --- end barrier ---
//   Each phase: one wave class on MFMA pipe, other on VALU pipe -> max not sum.
//   Parity: read base (i-1)&1, write base i&1 (same as R6; L0 phase-B reads
//   the WRITE parity). 514 intervals (2 drain). Manual x2 unroll -> parity
//   bases are compile-time (ds imm offsets). Packed f32x2 cell math (v_pk_*).
//   bf16x3 split GEMM + exp2-scaled gates unchanged (absmax 6.1e-5 known good).

#define TT 512
#define HH 64
#define NB 16
#define XP 516

typedef __bf16 bf16_t;
typedef bf16_t bf16x8 __attribute__((ext_vector_type(8)));
typedef float  f32x4  __attribute__((ext_vector_type(4)));
typedef float  f32x2  __attribute__((ext_vector_type(2)));

#define MFMA(A, B, C) __builtin_amdgcn_mfma_f32_16x16x32_bf16((A), (B), (C), 0, 0, 0)
#define RCPF(x) __builtin_amdgcn_rcpf(x)

#if __has_builtin(__builtin_amdgcn_exp2f)
#define EXP2F(x) __builtin_amdgcn_exp2f(x)
#else
__device__ __forceinline__ float EXP2F(float x) {
    float r;
    asm volatile("v_exp_f32 %0, %1" : "=v"(r) : "v"(x));
    return r;
}
#endif

#define SC_IFO (-1.4426950408889634f)   // -log2(e)
#define SC_G   ( 2.8853900817779268f)   // +2*log2(e)

__device__ __forceinline__ unsigned short f32_to_bf16_rne(float f) {
    unsigned int u = __builtin_bit_cast(unsigned int, f);
    unsigned int r = u + 0x7fffu + ((u >> 16) & 1u);
    return (unsigned short)(r >> 16);
}
__device__ __forceinline__ float bf16bits_to_f32(unsigned short s) {
    return __builtin_bit_cast(float, ((unsigned int)s) << 16);
}
__device__ __forceinline__ bf16_t bits_to_bf16(unsigned short u) {
    return __builtin_bit_cast(bf16_t, u);
}
// h split: hi RTZ, lo = residual RTZ (combined err ~2^-16 rel)
__device__ __forceinline__ void split_h(float f, unsigned short& hi, unsigned short& lo) {
    unsigned int u = __builtin_bit_cast(unsigned int, f);
    hi = (unsigned short)(u >> 16);
    float d = f - __builtin_bit_cast(float, u & 0xffff0000u);
    lo = (unsigned short)(__builtin_bit_cast(unsigned int, d) >> 16);
}
__device__ __forceinline__ void build_frags_scaled(const float* __restrict__ p, float sc,
                                                   bf16x8& hi, bf16x8& lo) {
    const float4 a = *(const float4*)p;
    const float4 b = *(const float4*)(p + 4);
    float v[8] = {a.x, a.y, a.z, a.w, b.x, b.y, b.z, b.w};
#pragma unroll
    for (int jj = 0; jj < 8; ++jj) {
        const float s = v[jj] * sc;
        unsigned short h = f32_to_bf16_rne(s);
        float d = s - bf16bits_to_f32(h);
        hi[jj] = bits_to_bf16(h);
        lo[jj] = bits_to_bf16(f32_to_bf16_rne(d));
    }
}

__device__ __forceinline__ f32x2 exp2v(f32x2 v) {
    f32x2 r; r[0] = EXP2F(v[0]); r[1] = EXP2F(v[1]); return r;
}
__device__ __forceinline__ f32x2 rcpv(f32x2 v) {
    f32x2 r; r[0] = RCPF(v[0]); r[1] = RCPF(v[1]); return r;
}
// Two cells (tau=0,1) on PRE-SCALED gates; packed f32x2 arithmetic.
__device__ __forceinline__ f32x2 cell2(const f32x4 a0, const f32x4 a1, f32x2* c) {
    f32x2 is = {a0[0], a1[0]}, fs = {a0[1], a1[1]};
    f32x2 gs = {a0[2], a1[2]}, os = {a0[3], a1[3]};
    const f32x2 pf = exp2v(fs);
    const f32x2 fg = rcpv(1.0f + pf);
    const f32x2 pi = exp2v(is);
    const f32x2 e2 = exp2v(gs);
    const f32x2 z  = (e2 - 1.0f) * rcpv((1.0f + pi) * (1.0f + e2));
    *c = fg * (*c) + z;
    const f32x2 po  = exp2v(os);
    const f32x2 e2c = exp2v((*c) * SC_G);
    return (e2c - 1.0f) * rcpv((1.0f + po) * (1.0f + e2c));
}

__global__ __launch_bounds__(1024, 4)
void lstm_phase_kernel(const float* __restrict__ x,
                       const float* __restrict__ Wih0, const float* __restrict__ Whh0,
                       const float* __restrict__ bih0, const float* __restrict__ bhh0,
                       const float* __restrict__ Wih1, const float* __restrict__ Whh1,
                       const float* __restrict__ bih1, const float* __restrict__ bhh1,
                       const float* __restrict__ Wfc,  const float* __restrict__ bfc,
                       float* __restrict__ out)
{
    __shared__ float xbuf[NB][XP];                   // 33 KB
    __shared__ unsigned short ht_hi[2][NB][128];     // 8 KB
    __shared__ unsigned short ht_lo[2][NB][128];     // 8 KB
    __shared__ float h1f[HH][NB + 1];                // 4.25 KB

    const int tid  = threadIdx.x;
    const int wv   = tid >> 6;       // 0..15; 0-7 L0 waves, 8-15 L1 waves
    const int lane = tid & 63;
    const int m    = lane & 15;
    const int q    = lane >> 4;
    const int m7   = m & 7;
    const int b0   = blockIdx.x * NB;
    const bool isL0 = (wv < 8);
    const int jg   = isL0 ? wv : (wv - 8);   // unit-group: units [8jg, 8jg+8)

    for (int i = tid; i < NB * TT / 4; i += 1024) {
        const int b  = i >> 7;
        const int t4 = i & 127;
        *(float4*)&xbuf[b][t4 * 4] = *(const float4*)&x[(size_t)(b0 + b) * TT + t4 * 4];
    }
    for (int i = tid; i < 2 * NB * 128; i += 1024) {
        (&ht_hi[0][0][0])[i] = 0;
        (&ht_lo[0][0][0])[i] = 0;
    }

    int roff[2][2];
#pragma unroll
    for (int L = 0; L < 2; ++L)
#pragma unroll
        for (int kt = 0; kt < 2; ++kt)
            roff[L][kt] = m * 128 + (((L << 3) | ((4 * kt + q) ^ m7)) * 8);
    const int wchunk0 = m * 128 + ((jg ^ m7) * 8) + q;        // L0 write (+4*tau)
    const int wchunk1 = m * 128 + ((8 | (jg ^ m7)) * 8) + q;  // L1 write (+4*tau)

    const int gate_m = m & 3;
    const float scA  = (gate_m == 2) ? SC_G : SC_IFO;
    unsigned short* const Hh = &ht_hi[0][0][0];
    unsigned short* const Hl = &ht_lo[0][0][0];

    __syncthreads();

    if (isL0) {
        // ============ L0 waves: units [8jg,8jg+8), 12 MFMA/step ============
        bf16x8 A0h[2][2], A0l[2][2];
        f32x4 bb0s[2], wx0s[2];
#pragma unroll
        for (int tau = 0; tau < 2; ++tau) {
            const int rowA = 64 * gate_m + (8 * jg + 4 * tau + (m >> 2));
#pragma unroll
            for (int kt = 0; kt < 2; ++kt)
                build_frags_scaled(&Whh0[rowA * HH + kt * 32 + q * 8], scA,
                                   A0h[tau][kt], A0l[tau][kt]);
#pragma unroll
            for (int r = 0; r < 4; ++r) {
                const int row = 64 * r + (8 * jg + 4 * tau + q);
                const float sc = (r == 2) ? SC_G : SC_IFO;
                bb0s[tau][r] = (bih0[row] + bhh0[row]) * sc;
                wx0s[tau][r] = Wih0[row] * sc;
            }
        }

        f32x2 c0 = {0.f, 0.f};
        f32x4 g0[2];                       // gates held across end-barrier

// Phase A: cells(I-1) + write h0(I-1) at parity WB. Phase B: MFMA gates(I)
// reading h0(I-1) from parity WB (published this interval).
#define L0_ITER(I, WB)                                                        \
        {                                                                     \
            if ((I) >= 1 && (I) <= TT) {                                      \
                const f32x2 hv = cell2(g0[0], g0[1], &c0);                    \
                unsigned short hb, lb;                                        \
                split_h(hv[0], hb, lb);                                       \
                Hh[(WB) + wchunk0] = hb;  Hl[(WB) + wchunk0] = lb;            \
                split_h(hv[1], hb, lb);                                       \
                Hh[(WB) + wchunk0 + 4] = hb;  Hl[(WB) + wchunk0 + 4] = lb;    \
            }                                                                 \
            __syncthreads();                                                  \
            if ((I) < TT) {                                                   \
                const float xv = xbuf[m][(I)];                                \
                bf16x8 bh[2], bl[2];                                          \
                bh[0] = *(const bf16x8*)(Hh + (WB) + roff[0][0]);             \
                bl[0] = *(const bf16x8*)(Hl + (WB) + roff[0][0]);             \
                bh[1] = *(const bf16x8*)(Hh + (WB) + roff[0][1]);             \
                bl[1] = *(const bf16x8*)(Hl + (WB) + roff[0][1]);             \
                _Pragma("unroll")                                             \
                for (int tau = 0; tau < 2; ++tau) {                           \
                    f32x4 a;                                                  \
                    _Pragma("unroll")                                         \
                    for (int r = 0; r < 4; ++r)                               \
                        a[r] = __builtin_fmaf(xv, wx0s[tau][r], bb0s[tau][r]);\
                    _Pragma("unroll")                                         \
                    for (int kt = 0; kt < 2; ++kt) {                          \
                        a = MFMA(A0h[tau][kt], bh[kt], a);                    \
                        a = MFMA(A0h[tau][kt], bl[kt], a);                    \
                        a = MFMA(A0l[tau][kt], bh[kt], a);                    \
                    }                                                         \
                    g0[tau] = a;                                              \
                }                                                             \
            }                                                                 \
            __syncthreads();                                                  \
        }

#pragma unroll 1
        for (int ib = 0; ib < TT + 2; ib += 2) {
            L0_ITER(ib, 0);          // even interval: write parity 0
            L0_ITER(ib + 1, 2048);   // odd interval:  write parity 1
        }
    } else {
        // ============ L1 waves: units [8jg,8jg+8), 24 MFMA/step ============
        bf16x8 A1h[2][4], A1l[2][4];    // kt 0-1 Wih1 (eats h0), 2-3 Whh1 (eats h1)
        f32x4 bb1s[2];
#pragma unroll
        for (int tau = 0; tau < 2; ++tau) {
            const int rowA = 64 * gate_m + (8 * jg + 4 * tau + (m >> 2));
#pragma unroll
            for (int kt = 0; kt < 2; ++kt)
                build_frags_scaled(&Wih1[rowA * HH + kt * 32 + q * 8], scA,
                                   A1h[tau][kt], A1l[tau][kt]);
#pragma unroll
            for (int kt = 0; kt < 2; ++kt)
                build_frags_scaled(&Whh1[rowA * HH + kt * 32 + q * 8], scA,
                                   A1h[tau][2 + kt], A1l[tau][2 + kt]);
#pragma unroll
            for (int r = 0; r < 4; ++r) {
                const int row = 64 * r + (8 * jg + 4 * tau + q);
                const float sc = (r == 2) ? SC_G : SC_IFO;
                bb1s[tau][r] = (bih1[row] + bhh1[row]) * sc;
            }
        }

        f32x2 c1 = {0.f, 0.f};

// Phase A: MFMA gates(I-2) reading parity RB = (I-1)&1 {h0(I-2), h1(I-3)}.
// Phase B: cells(I-2) + write h1(I-2) at parity WB = I&1.
#define L1_ITER(I, RB, WB)                                                    \
        {                                                                     \
            f32x4 a1[2];                                                      \
            if ((I) >= 2) {                                                   \
                bf16x8 bh[4], bl[4];                                          \
                bh[0] = *(const bf16x8*)(Hh + (RB) + roff[0][0]);             \
                bl[0] = *(const bf16x8*)(Hl + (RB) + roff[0][0]);             \
                bh[1] = *(const bf16x8*)(Hh + (RB) + roff[0][1]);             \
                bl[1] = *(const bf16x8*)(Hl + (RB) + roff[0][1]);             \
                bh[2] = *(const bf16x8*)(Hh + (RB) + roff[1][0]);             \
                bl[2] = *(const bf16x8*)(Hl + (RB) + roff[1][0]);             \
                bh[3] = *(const bf16x8*)(Hh + (RB) + roff[1][1]);             \
                bl[3] = *(const bf16x8*)(Hl + (RB) + roff[1][1]);             \
                _Pragma("unroll")                                             \
                for (int tau = 0; tau < 2; ++tau) {                           \
                    f32x4 a = MFMA(A1h[tau][0], bh[0], bb1s[tau]);            \
                    a = MFMA(A1h[tau][0], bl[0], a);                          \
                    a = MFMA(A1l[tau][0], bh[0], a);                          \
                    a = MFMA(A1h[tau][1], bh[1], a);                          \
                    a = MFMA(A1h[tau][1], bl[1], a);                          \
                    a = MFMA(A1l[tau][1], bh[1], a);                          \
                    _Pragma("unroll")                                         \
                    for (int kt = 0; kt < 2; ++kt) {                          \
                        a = MFMA(A1h[tau][2 + kt], bh[2 + kt], a);            \
                        a = MFMA(A1h[tau][2 + kt], bl[2 + kt], a);            \
                        a = MFMA(A1l[tau][2 + kt], bh[2 + kt], a);            \
                    }                                                         \
                    a1[tau] = a;                                              \
                }                                                             \
            }                                                                 \
            __syncthreads();                                                  \
            if ((I) >= 2) {                                                   \
                const f32x2 hv = cell2(a1[0], a1[1], &c1);                    \
                unsigned short hb, lb;                                        \
                split_h(hv[0], hb, lb);                                       \
                Hh[(WB) + wchunk1] = hb;  Hl[(WB) + wchunk1] = lb;            \
                split_h(hv[1], hb, lb);                                       \
                Hh[(WB) + wchunk1 + 4] = hb;  Hl[(WB) + wchunk1 + 4] = lb;    \
                if ((I) == TT + 1) {                                          \
                    h1f[8 * jg + q][m]     = hv[0];                           \
                    h1f[8 * jg + 4 + q][m] = hv[1];                           \
                }                                                             \
            }                                                                 \
            __syncthreads();                                                  \
        }

#pragma unroll 1
        for (int ib = 0; ib < TT + 2; ib += 2) {
            L1_ITER(ib, 2048, 0);        // even: read parity 1, write parity 0
            L1_ITER(ib + 1, 0, 2048);    // odd:  read parity 0, write parity 1
        }
    }

    // ---- FC epilogue: out[b] = h1(T-1)[b] . Wfc + bfc ----
    if (tid < NB) {
        float s = bfc[0];
#pragma unroll
        for (int u = 0; u < HH; ++u) s = fmaf(h1f[u][tid], Wfc[u], s);
        out[b0 + tid] = s;
    }
}

extern "C" void kernel_launch(void* const* d_in, const int* in_sizes, int n_in,
                              void* d_out, int out_size, void* d_ws, size_t ws_size,
                              hipStream_t stream) {
    const float* x    = (const float*)d_in[0];
    const float* Wih0 = (const float*)d_in[1];
    const float* Whh0 = (const float*)d_in[2];
    const float* bih0 = (const float*)d_in[3];
    const float* bhh0 = (const float*)d_in[4];
    const float* Wih1 = (const float*)d_in[5];
    const float* Whh1 = (const float*)d_in[6];
    const float* bih1 = (const float*)d_in[7];
    const float* bhh1 = (const float*)d_in[8];
    const float* Wfc  = (const float*)d_in[9];
    const float* bfc  = (const float*)d_in[10];

    lstm_phase_kernel<<<dim3(4096 / NB), dim3(1024), 0, stream>>>(
        x, Wih0, Whh0, bih0, bhh0, Wih1, Whh1, bih1, bhh1, Wfc, bfc, (float*)d_out);
}

// Round 8
// 704.254 us; speedup vs baseline: 1.0014x; 1.0014x over previous
//
#include <hip/hip_runtime.h>

// LSTMForecaster: B=4096, T=512, D=1, H=64, 2 layers + FC(64->1).
// R8: balanced waves (no specialization), 1 barrier/step.
//   R7 regressed (2 barriers = 2x drains, no overlap). R6 re-analysis with
//   VALUBusy⊇MFMA: idle was 41%, driven by L0(12-MFMA) vs L1(24-MFMA) wave
//   skew at the shared barrier + exposed 12-deep MFMA chains.
//   Fix: all 16 waves identical -- wave w owns units [4w,4w+4) of BOTH layers
//   (one unit-major 16-row tile per layer): 6 L0-MFMA + 12 L1-MFMA = 18/wave,
//   zero barrier skew. L0(t) and L1(t-1) share the h0(t-1) B-frags (8 reads).
//   Accum chains split (3+3 / 6+6 partials) to halve serial MFMA latency.
//   Edge steps branchless: t==0 zeroes L1 cell result+state.
//   bf16x3 split GEMM + exp2-scaled gates + packed cell (absmax 6.1e-5 good).

#define TT 512
#define HH 64
#define NB 16
#define XP 516

typedef __bf16 bf16_t;
typedef bf16_t bf16x8 __attribute__((ext_vector_type(8)));
typedef float  f32x4  __attribute__((ext_vector_type(4)));
typedef float  f32x2  __attribute__((ext_vector_type(2)));

#define MFMA(A, B, C) __builtin_amdgcn_mfma_f32_16x16x32_bf16((A), (B), (C), 0, 0, 0)
#define RCPF(x) __builtin_amdgcn_rcpf(x)

#if __has_builtin(__builtin_amdgcn_exp2f)
#define EXP2F(x) __builtin_amdgcn_exp2f(x)
#else
__device__ __forceinline__ float EXP2F(float x) {
    float r;
    asm volatile("v_exp_f32 %0, %1" : "=v"(r) : "v"(x));
    return r;
}
#endif

#define SC_IFO (-1.4426950408889634f)   // -log2(e)
#define SC_G   ( 2.8853900817779268f)   // +2*log2(e)

__device__ __forceinline__ unsigned short f32_to_bf16_rne(float f) {
    unsigned int u = __builtin_bit_cast(unsigned int, f);
    unsigned int r = u + 0x7fffu + ((u >> 16) & 1u);
    return (unsigned short)(r >> 16);
}
__device__ __forceinline__ float bf16bits_to_f32(unsigned short s) {
    return __builtin_bit_cast(float, ((unsigned int)s) << 16);
}
__device__ __forceinline__ bf16_t bits_to_bf16(unsigned short u) {
    return __builtin_bit_cast(bf16_t, u);
}
// h split: hi RTZ, lo = residual RTZ (combined err ~2^-16 rel)
__device__ __forceinline__ void split_h(float f, unsigned short& hi, unsigned short& lo) {
    unsigned int u = __builtin_bit_cast(unsigned int, f);
    hi = (unsigned short)(u >> 16);
    float d = f - __builtin_bit_cast(float, u & 0xffff0000u);
    lo = (unsigned short)(__builtin_bit_cast(unsigned int, d) >> 16);
}
__device__ __forceinline__ void build_frags_scaled(const float* __restrict__ p, float sc,
                                                   bf16x8& hi, bf16x8& lo) {
    const float4 a = *(const float4*)p;
    const float4 b = *(const float4*)(p + 4);
    float v[8] = {a.x, a.y, a.z, a.w, b.x, b.y, b.z, b.w};
#pragma unroll
    for (int jj = 0; jj < 8; ++jj) {
        const float s = v[jj] * sc;
        unsigned short h = f32_to_bf16_rne(s);
        float d = s - bf16bits_to_f32(h);
        hi[jj] = bits_to_bf16(h);
        lo[jj] = bits_to_bf16(f32_to_bf16_rne(d));
    }
}

__device__ __forceinline__ f32x2 exp2v(f32x2 v) {
    f32x2 r; r[0] = EXP2F(v[0]); r[1] = EXP2F(v[1]); return r;
}
__device__ __forceinline__ f32x2 rcpv(f32x2 v) {
    f32x2 r; r[0] = RCPF(v[0]); r[1] = RCPF(v[1]); return r;
}
// Two cells (lane's L0 cell, L1 cell) on PRE-SCALED gates, packed f32x2.
__device__ __forceinline__ f32x2 cell2(const f32x4 a0, const f32x4 a1, f32x2* c) {
    f32x2 is = {a0[0], a1[0]}, fs = {a0[1], a1[1]};
    f32x2 gs = {a0[2], a1[2]}, os = {a0[3], a1[3]};
    const f32x2 pf = exp2v(fs);
    const f32x2 fg = rcpv(1.0f + pf);
    const f32x2 pi = exp2v(is);
    const f32x2 e2 = exp2v(gs);
    const f32x2 z  = (e2 - 1.0f) * rcpv((1.0f + pi) * (1.0f + e2));
    *c = fg * (*c) + z;
    const f32x2 po  = exp2v(os);
    const f32x2 e2c = exp2v((*c) * SC_G);
    return (e2c - 1.0f) * rcpv((1.0f + po) * (1.0f + e2c));
}

__global__ __launch_bounds__(1024, 4)
void lstm_bal_kernel(const float* __restrict__ x,
                     const float* __restrict__ Wih0, const float* __restrict__ Whh0,
                     const float* __restrict__ bih0, const float* __restrict__ bhh0,
                     const float* __restrict__ Wih1, const float* __restrict__ Whh1,
                     const float* __restrict__ bih1, const float* __restrict__ bhh1,
                     const float* __restrict__ Wfc,  const float* __restrict__ bfc,
                     float* __restrict__ out)
{
    __shared__ float xbuf[NB][XP];                   // 33 KB
    // h-state: [parity][b][16 chunks x 8 shorts]; chunks 0..7 h0 (k=u), 8..15 h1;
    // physical chunk = (c&8) | ((c&7) ^ (b&7)).
    __shared__ unsigned short ht_hi[2][NB][128];     // 8 KB
    __shared__ unsigned short ht_lo[2][NB][128];     // 8 KB
    __shared__ float h1f[HH][NB + 1];                // 4.25 KB

    const int tid  = threadIdx.x;
    const int w    = tid >> 6;       // 0..15: owns units [4w,4w+4) of BOTH layers
    const int lane = tid & 63;
    const int m    = lane & 15;      // batch col (B/C) & A-frag row-in-tile
    const int q    = lane >> 4;      // C-frag unit_local; A/B k-quad
    const int m7   = m & 7;
    const int b0   = blockIdx.x * NB;

    for (int i = tid; i < NB * TT / 4; i += 1024) {
        const int b  = i >> 7;
        const int t4 = i & 127;
        *(float4*)&xbuf[b][t4 * 4] = *(const float4*)&x[(size_t)(b0 + b) * TT + t4 * 4];
    }
    for (int i = tid; i < 2 * NB * 128; i += 1024) {
        (&ht_hi[0][0][0])[i] = 0;
        (&ht_lo[0][0][0])[i] = 0;
    }

    // ---- read offsets (shorts within one parity block of 2048) ----
    int roff[2][2];
#pragma unroll
    for (int L = 0; L < 2; ++L)
#pragma unroll
        for (int kt = 0; kt < 2; ++kt)
            roff[L][kt] = m * 128 + (((L << 3) | ((4 * kt + q) ^ m7)) * 8);
    // ---- write offsets: lane's unit u = 4w + q ----
    const int uu   = 4 * w + q;
    const int lc   = uu >> 3;                                  // logical chunk low3
    const int woff0 = m * 128 + ((lc ^ m7) * 8) + (uu & 7);        // h0
    const int woff1 = m * 128 + (((8 | (lc ^ m7))) * 8) + (uu & 7); // h1

    // ---- A-fragments: unit-major 16-row tile per layer ----
    // tile row m -> unit 4w + (m>>2), gate m&3; orig row = 64*gate + unit.
    const int gate_m = m & 3;
    const float scA  = (gate_m == 2) ? SC_G : SC_IFO;
    const int rowA   = 64 * gate_m + 4 * w + (m >> 2);

    bf16x8 A0h[2], A0l[2];           // Whh0, kt 0..1
    bf16x8 A1h[4], A1l[4];           // kt 0-1: Wih1 (eats h0), kt 2-3: Whh1 (eats h1)
#pragma unroll
    for (int kt = 0; kt < 2; ++kt)
        build_frags_scaled(&Whh0[rowA * HH + kt * 32 + q * 8], scA, A0h[kt], A0l[kt]);
#pragma unroll
    for (int kt = 0; kt < 2; ++kt)
        build_frags_scaled(&Wih1[rowA * HH + kt * 32 + q * 8], scA, A1h[kt], A1l[kt]);
#pragma unroll
    for (int kt = 0; kt < 2; ++kt)
        build_frags_scaled(&Whh1[rowA * HH + kt * 32 + q * 8], scA, A1h[2 + kt], A1l[2 + kt]);

    // ---- per-lane bias/wx for C-frag rows: reg r = gate, unit = 4w + q ----
    f32x4 bb0s, wx0s, bb1s;
#pragma unroll
    for (int r = 0; r < 4; ++r) {
        const int row = 64 * r + 4 * w + q;
        const float sc = (r == 2) ? SC_G : SC_IFO;
        bb0s[r] = (bih0[row] + bhh0[row]) * sc;
        wx0s[r] = Wih0[row] * sc;
        bb1s[r] = (bih1[row] + bhh1[row]) * sc;
    }

    f32x2 c01 = {0.f, 0.f};
    unsigned short* const Hh = &ht_hi[0][0][0];
    unsigned short* const Hl = &ht_lo[0][0][0];

    __syncthreads();

#pragma unroll 1
    for (int t = 0; t <= TT; ++t) {
        const int rb = ((t + 1) & 1) * 2048;    // old state {h0(t-1), h1(t-2)}
        const int wb = (t & 1) * 2048;          // new state {h0(t), h1(t-1)}

        // ---- all B-frag reads (h0 frags shared by L0(t) and L1(t-1)) ----
        bf16x8 h0h[2], h0l[2], h1h[2], h1l[2];
#pragma unroll
        for (int kt = 0; kt < 2; ++kt) {
            h0h[kt] = *(const bf16x8*)(Hh + rb + roff[0][kt]);
            h0l[kt] = *(const bf16x8*)(Hl + rb + roff[0][kt]);
            h1h[kt] = *(const bf16x8*)(Hh + rb + roff[1][kt]);
            h1l[kt] = *(const bf16x8*)(Hl + rb + roff[1][kt]);
        }
        const float xv = xbuf[m][(t < TT) ? t : 0];

        // ---- L0 gates(t): 6 MFMA as two 3-deep chains ----
        f32x4 a0v, z0 = {0.f, 0.f, 0.f, 0.f};
#pragma unroll
        for (int r = 0; r < 4; ++r) a0v[r] = __builtin_fmaf(xv, wx0s[r], bb0s[r]);
        a0v = MFMA(A0h[0], h0h[0], a0v);
        a0v = MFMA(A0h[0], h0l[0], a0v);
        a0v = MFMA(A0l[0], h0h[0], a0v);
        z0  = MFMA(A0h[1], h0h[1], z0);
        z0  = MFMA(A0h[1], h0l[1], z0);
        z0  = MFMA(A0l[1], h0h[1], z0);
        a0v = a0v + z0;

        // ---- L1 gates(t-1): 12 MFMA as two 6-deep chains ----
        f32x4 p = bb1s, s = {0.f, 0.f, 0.f, 0.f};
#pragma unroll
        for (int kt = 0; kt < 2; ++kt) {           // eats h0(t-1)
            p = MFMA(A1h[kt], h0h[kt], p);
            p = MFMA(A1h[kt], h0l[kt], p);
            p = MFMA(A1l[kt], h0h[kt], p);
        }
#pragma unroll
        for (int kt = 0; kt < 2; ++kt) {           // eats h1(t-2)
            s = MFMA(A1h[2 + kt], h1h[kt], s);
            s = MFMA(A1h[2 + kt], h1l[kt], s);
            s = MFMA(A1l[2 + kt], h1h[kt], s);
        }
        const f32x4 a1v = p + s;

        // ---- both cells, packed ----
        f32x2 hv = cell2(a0v, a1v, &c01);
        if (t == 0) {            // L1 lane inactive at t=0: h1(-1)=0, c1 stays 0
            hv[1] = 0.0f;
            c01[1] = 0.0f;
        }
        if (t == TT) h1f[uu][m] = hv[1];            // exact fp32 h1(T-1) for FC

        unsigned short hb, lb;
        split_h(hv[0], hb, lb);
        Hh[wb + woff0] = hb;  Hl[wb + woff0] = lb;  // h0(t)
        split_h(hv[1], hb, lb);
        Hh[wb + woff1] = hb;  Hl[wb + woff1] = lb;  // h1(t-1)

        __syncthreads();
    }

    // ---- FC epilogue: out[b] = h1(T-1)[b] . Wfc + bfc ----
    if (tid < NB) {
        float sacc = bfc[0];
#pragma unroll
        for (int u = 0; u < HH; ++u) sacc = fmaf(h1f[u][tid], Wfc[u], sacc);
        out[b0 + tid] = sacc;
    }
}

extern "C" void kernel_launch(void* const* d_in, const int* in_sizes, int n_in,
                              void* d_out, int out_size, void* d_ws, size_t ws_size,
                              hipStream_t stream) {
    const float* x    = (const float*)d_in[0];
    const float* Wih0 = (const float*)d_in[1];
    const float* Whh0 = (const float*)d_in[2];
    const float* bih0 = (const float*)d_in[3];
    const float* bhh0 = (const float*)d_in[4];
    const float* Wih1 = (const float*)d_in[5];
    const float* Whh1 = (const float*)d_in[6];
    const float* bih1 = (const float*)d_in[7];
    const float* bhh1 = (const float*)d_in[8];
    const float* Wfc  = (const float*)d_in[9];
    const float* bfc  = (const float*)d_in[10];

    lstm_bal_kernel<<<dim3(4096 / NB), dim3(1024), 0, stream>>>(
        x, Wih0, Whh0, bih0, bhh0, Wih1, Whh1, bih1, bhh1, Wfc, bfc, (float*)d_out);
}

// Round 9
// 555.275 us; speedup vs baseline: 1.2701x; 1.2683x over previous
//
#include <hip/hip_runtime.h>

// LSTMForecaster: B=4096, T=512, D=1, H=64, 2 layers + FC(64->1).
// R9: LDS-traffic attack. R8 evidence: conflict counter ∝ b128 count; LDS read
//   pipe (~17 cyc/b128 incl. structural penalty) exceeded the MFMA floor.
//   Two cuts:
//   (1) h stored as SINGLE bf16 plane (RNE); precision kept on the weight side
//       only: 2-term GEMM  Whi*h + Wlo*h  (W split exact, h rounded 2^-10 rms).
//       -> halves reads, cuts MFMA 288->192/CU (931 cyc/SIMD floor).
//       Predicted absmax ~1.5e-4 (< 3.78e-4 threshold). Fallback if fail:
//       restore lo-plane for h1 only.
//   (2) 12 waves (768 thr), specialized AND balanced: 4 L0 waves x 16 units
//       (16 MFMA, 2 b128) + 8 L1 waves x 8 units (16 MFMA, 4 b128).
//       Reads: 40 b128/step/CU (~700 cyc) < MFMA 931. Zero wave skew.
//   Everything else as R6/R8: unit-major tiles (cell register-local), XOR
//   swizzle, exp2-folded gate scales, packed cells, 1 barrier/step, L1 lags 1.

#define TT 512
#define HH 64
#define NB 16
#define XP 516

typedef __bf16 bf16_t;
typedef bf16_t bf16x8 __attribute__((ext_vector_type(8)));
typedef float  f32x4  __attribute__((ext_vector_type(4)));
typedef float  f32x2  __attribute__((ext_vector_type(2)));

#define MFMA(A, B, C) __builtin_amdgcn_mfma_f32_16x16x32_bf16((A), (B), (C), 0, 0, 0)
#define RCPF(x) __builtin_amdgcn_rcpf(x)

#if __has_builtin(__builtin_amdgcn_exp2f)
#define EXP2F(x) __builtin_amdgcn_exp2f(x)
#else
__device__ __forceinline__ float EXP2F(float x) {
    float r;
    asm volatile("v_exp_f32 %0, %1" : "=v"(r) : "v"(x));
    return r;
}
#endif

#define SC_IFO (-1.4426950408889634f)   // -log2(e)
#define SC_G   ( 2.8853900817779268f)   // +2*log2(e)

__device__ __forceinline__ unsigned short f32_to_bf16_rne(float f) {
    unsigned int u = __builtin_bit_cast(unsigned int, f);
    unsigned int r = u + 0x7fffu + ((u >> 16) & 1u);
    return (unsigned short)(r >> 16);
}
__device__ __forceinline__ float bf16bits_to_f32(unsigned short s) {
    return __builtin_bit_cast(float, ((unsigned int)s) << 16);
}
__device__ __forceinline__ bf16_t bits_to_bf16(unsigned short u) {
    return __builtin_bit_cast(bf16_t, u);
}
// weight split with per-row scale folded in (one-time; both halves RNE)
__device__ __forceinline__ void build_frags_scaled(const float* __restrict__ p, float sc,
                                                   bf16x8& hi, bf16x8& lo) {
    const float4 a = *(const float4*)p;
    const float4 b = *(const float4*)(p + 4);
    float v[8] = {a.x, a.y, a.z, a.w, b.x, b.y, b.z, b.w};
#pragma unroll
    for (int jj = 0; jj < 8; ++jj) {
        const float s = v[jj] * sc;
        unsigned short h = f32_to_bf16_rne(s);
        float d = s - bf16bits_to_f32(h);
        hi[jj] = bits_to_bf16(h);
        lo[jj] = bits_to_bf16(f32_to_bf16_rne(d));
    }
}

__device__ __forceinline__ f32x2 exp2v(f32x2 v) {
    f32x2 r; r[0] = EXP2F(v[0]); r[1] = EXP2F(v[1]); return r;
}
__device__ __forceinline__ f32x2 rcpv(f32x2 v) {
    f32x2 r; r[0] = RCPF(v[0]); r[1] = RCPF(v[1]); return r;
}
// Two cells on PRE-SCALED gates (is,fs,os scaled -log2e; gs scaled +2log2e).
__device__ __forceinline__ f32x2 cell2(const f32x4 a0, const f32x4 a1, f32x2* c) {
    f32x2 is = {a0[0], a1[0]}, fs = {a0[1], a1[1]};
    f32x2 gs = {a0[2], a1[2]}, os = {a0[3], a1[3]};
    const f32x2 pf = exp2v(fs);
    const f32x2 fg = rcpv(1.0f + pf);
    const f32x2 pi = exp2v(is);
    const f32x2 e2 = exp2v(gs);
    const f32x2 z  = (e2 - 1.0f) * rcpv((1.0f + pi) * (1.0f + e2));
    *c = fg * (*c) + z;
    const f32x2 po  = exp2v(os);
    const f32x2 e2c = exp2v((*c) * SC_G);
    return (e2c - 1.0f) * rcpv((1.0f + po) * (1.0f + e2c));
}

__global__ __launch_bounds__(768, 3)
void lstm_2t_kernel(const float* __restrict__ x,
                    const float* __restrict__ Wih0, const float* __restrict__ Whh0,
                    const float* __restrict__ bih0, const float* __restrict__ bhh0,
                    const float* __restrict__ Wih1, const float* __restrict__ Whh1,
                    const float* __restrict__ bih1, const float* __restrict__ bhh1,
                    const float* __restrict__ Wfc,  const float* __restrict__ bfc,
                    float* __restrict__ out)
{
    __shared__ float xbuf[NB][XP];                   // 33 KB
    // h-state, single bf16 plane: [parity][b][16 chunks x 8 shorts];
    // chunks 0..7 = h0, 8..15 = h1; physical chunk = (c&8) | ((c&7)^(b&7)).
    __shared__ unsigned short ht[2][NB][128];        // 8 KB
    __shared__ float h1f[HH][NB + 1];                // 4.25 KB

    const int tid  = threadIdx.x;
    const int wv   = tid >> 6;       // 0..11: 0-3 L0 waves, 4-11 L1 waves
    const int lane = tid & 63;
    const int m    = lane & 15;      // batch col (B/C frag) & A-frag row-in-tile
    const int q    = lane >> 4;      // C-frag unit_local; A/B k-quad
    const int m7   = m & 7;
    const int b0   = blockIdx.x * NB;
    const bool isL0 = (wv < 4);

    // ---- stage x (coalesced float4) ----
    for (int i = tid; i < NB * TT / 4; i += 768) {
        const int b  = i >> 7;
        const int t4 = i & 127;
        *(float4*)&xbuf[b][t4 * 4] = *(const float4*)&x[(size_t)(b0 + b) * TT + t4 * 4];
    }
    // ---- zero both parities ----
    for (int i = tid; i < 2 * NB * 128; i += 768) (&ht[0][0][0])[i] = 0;

    // ---- read offsets (shorts within one parity block of 2048) ----
    int roff[2][2];
#pragma unroll
    for (int L = 0; L < 2; ++L)
#pragma unroll
        for (int kt = 0; kt < 2; ++kt)
            roff[L][kt] = m * 128 + (((L << 3) | ((4 * kt + q) ^ m7)) * 8);

    const int gate_m = m & 3;
    const float scA  = (gate_m == 2) ? SC_G : SC_IFO;
    unsigned short* const Hs = &ht[0][0][0];

    __syncthreads();

    if (isL0) {
        // ===== L0 waves: units [16w,16w+16) as 4 unit-major tiles, 16 MFMA =====
        const int w = wv;
        bf16x8 Ah[4][2], Al[4][2];          // [tau][kt] of Whh0 (hi/lo split)
        f32x4 bb0s[4], wx0s[4];
        int woff[4];
#pragma unroll
        for (int tau = 0; tau < 4; ++tau) {
            const int rowA = 64 * gate_m + 16 * w + 4 * tau + (m >> 2);
#pragma unroll
            for (int kt = 0; kt < 2; ++kt)
                build_frags_scaled(&Whh0[rowA * HH + kt * 32 + q * 8], scA,
                                   Ah[tau][kt], Al[tau][kt]);
#pragma unroll
            for (int r = 0; r < 4; ++r) {
                const int row = 64 * r + 16 * w + 4 * tau + q;
                const float sc = (r == 2) ? SC_G : SC_IFO;
                bb0s[tau][r] = (bih0[row] + bhh0[row]) * sc;
                wx0s[tau][r] = Wih0[row] * sc;
            }
            const int u = 16 * w + 4 * tau + q;
            woff[tau] = m * 128 + (((u >> 3) ^ m7) * 8) + (u & 7);
        }

        f32x2 cA = {0.f, 0.f}, cB = {0.f, 0.f};

#pragma unroll 1
        for (int t = 0; t <= TT; ++t) {
            const int rb = ((t + 1) & 1) * 2048;
            const int wb = (t & 1) * 2048;

            bf16x8 h0[2];
            h0[0] = *(const bf16x8*)(Hs + rb + roff[0][0]);
            h0[1] = *(const bf16x8*)(Hs + rb + roff[0][1]);
            const float xv = xbuf[m][(t < TT) ? t : 0];

            f32x4 a[4];
#pragma unroll
            for (int tau = 0; tau < 4; ++tau) {
                f32x4 p;
#pragma unroll
                for (int r = 0; r < 4; ++r)
                    p[r] = __builtin_fmaf(xv, wx0s[tau][r], bb0s[tau][r]);
                f32x4 z = {0.f, 0.f, 0.f, 0.f};
                p = MFMA(Ah[tau][0], h0[0], p);
                p = MFMA(Al[tau][0], h0[0], p);
                z = MFMA(Ah[tau][1], h0[1], z);
                z = MFMA(Al[tau][1], h0[1], z);
                a[tau] = p + z;
            }

            const f32x2 hv0 = cell2(a[0], a[1], &cA);
            const f32x2 hv1 = cell2(a[2], a[3], &cB);
            Hs[wb + woff[0]] = f32_to_bf16_rne(hv0[0]);
            Hs[wb + woff[1]] = f32_to_bf16_rne(hv0[1]);
            Hs[wb + woff[2]] = f32_to_bf16_rne(hv1[0]);
            Hs[wb + woff[3]] = f32_to_bf16_rne(hv1[1]);

            __syncthreads();
        }
    } else {
        // ===== L1 waves: units [8w,8w+8) as 2 unit-major tiles, 16 MFMA =====
        const int w = wv - 4;
        bf16x8 Ah[2][4], Al[2][4];   // [tau][kt]: kt0-1 Wih1 (eats h0), kt2-3 Whh1 (eats h1)
        f32x4 bb1s[2];
        int woff[2], uu[2];
#pragma unroll
        for (int tau = 0; tau < 2; ++tau) {
            const int rowA = 64 * gate_m + 8 * w + 4 * tau + (m >> 2);
#pragma unroll
            for (int kt = 0; kt < 2; ++kt)
                build_frags_scaled(&Wih1[rowA * HH + kt * 32 + q * 8], scA,
                                   Ah[tau][kt], Al[tau][kt]);
#pragma unroll
            for (int kt = 0; kt < 2; ++kt)
                build_frags_scaled(&Whh1[rowA * HH + kt * 32 + q * 8], scA,
                                   Ah[tau][2 + kt], Al[tau][2 + kt]);
#pragma unroll
            for (int r = 0; r < 4; ++r) {
                const int row = 64 * r + 8 * w + 4 * tau + q;
                const float sc = (r == 2) ? SC_G : SC_IFO;
                bb1s[tau][r] = (bih1[row] + bhh1[row]) * sc;
            }
            const int u = 8 * w + 4 * tau + q;
            uu[tau]   = u;
            woff[tau] = m * 128 + ((8 | ((u >> 3) ^ m7)) * 8) + (u & 7);
        }

        f32x2 c1 = {0.f, 0.f};

#pragma unroll 1
        for (int t = 0; t <= TT; ++t) {
            const int rb = ((t + 1) & 1) * 2048;
            const int wb = (t & 1) * 2048;

            bf16x8 h0[2], h1[2];
            h0[0] = *(const bf16x8*)(Hs + rb + roff[0][0]);
            h0[1] = *(const bf16x8*)(Hs + rb + roff[0][1]);
            h1[0] = *(const bf16x8*)(Hs + rb + roff[1][0]);
            h1[1] = *(const bf16x8*)(Hs + rb + roff[1][1]);

            f32x4 a[2];
#pragma unroll
            for (int tau = 0; tau < 2; ++tau) {
                f32x4 p = bb1s[tau];
                f32x4 s = {0.f, 0.f, 0.f, 0.f};
                p = MFMA(Ah[tau][0], h0[0], p);        // Wih1 . h0(t-1)
                p = MFMA(Al[tau][0], h0[0], p);
                p = MFMA(Ah[tau][1], h0[1], p);
                p = MFMA(Al[tau][1], h0[1], p);
                s = MFMA(Ah[tau][2], h1[0], s);        // Whh1 . h1(t-2)
                s = MFMA(Al[tau][2], h1[0], s);
                s = MFMA(Ah[tau][3], h1[1], s);
                s = MFMA(Al[tau][3], h1[1], s);
                a[tau] = p + s;
            }

            f32x2 hv = cell2(a[0], a[1], &c1);
            if (t == 0) {                       // h1(-1) = 0, c1 stays 0
                hv[0] = 0.f; hv[1] = 0.f;
                c1[0] = 0.f; c1[1] = 0.f;
            }
            if (t == TT) {                      // exact fp32 h1(T-1) for FC
                h1f[uu[0]][m] = hv[0];
                h1f[uu[1]][m] = hv[1];
            }
            Hs[wb + woff[0]] = f32_to_bf16_rne(hv[0]);
            Hs[wb + woff[1]] = f32_to_bf16_rne(hv[1]);

            __syncthreads();
        }
    }

    // ---- FC epilogue: out[b] = h1(T-1)[b] . Wfc + bfc ----
    if (tid < NB) {
        float sacc = bfc[0];
#pragma unroll
        for (int u = 0; u < HH; ++u) sacc = fmaf(h1f[u][tid], Wfc[u], sacc);
        out[b0 + tid] = sacc;
    }
}

extern "C" void kernel_launch(void* const* d_in, const int* in_sizes, int n_in,
                              void* d_out, int out_size, void* d_ws, size_t ws_size,
                              hipStream_t stream) {
    const float* x    = (const float*)d_in[0];
    const float* Wih0 = (const float*)d_in[1];
    const float* Whh0 = (const float*)d_in[2];
    const float* bih0 = (const float*)d_in[3];
    const float* bhh0 = (const float*)d_in[4];
    const float* Wih1 = (const float*)d_in[5];
    const float* Whh1 = (const float*)d_in[6];
    const float* bih1 = (const float*)d_in[7];
    const float* bhh1 = (const float*)d_in[8];
    const float* Wfc  = (const float*)d_in[9];
    const float* bfc  = (const float*)d_in[10];

    lstm_2t_kernel<<<dim3(4096 / NB), dim3(768), 0, stream>>>(
        x, Wih0, Whh0, bih0, bhh0, Wih1, Whh1, bih1, bhh1, Wfc, bfc, (float*)d_out);
}

// Round 10
// 518.696 us; speedup vs baseline: 1.3596x; 1.0705x over previous
//
#include <hip/hip_runtime.h>

// LSTMForecaster: B=4096, T=512, D=1, H=64, 2 layers + FC(64->1).
// R10: FREE-RUNNING waves -- no __syncthreads in the main loop.
//   R6..R9 post-mortems: with barrier lock-step, step = SUM of pipe times
//   (MFMA 931 + LDS ~760 + VALU ~550 = 2598 measured); cross-wave pipe overlap
//   (m114) never engages because all waves are in the same phase.
//   Fix: per-wave step loops synced only by LDS flags (monotone step counters,
//   one per producer wave). h0 ring: 8 slots; h1 ring: 2 slots.
//     L0 wave w, step t: poll min(f0)>=t-1 -> read h0(t-1) -> MFMA ->
//       [poll min(f1)>=t-8 (back-pressure, hidden under MFMA)] -> cells ->
//       write h0(t) slot t&7 -> s_waitcnt lgkmcnt(0) -> publish f0[w]=t.
//     L1 wave u, step tau: poll f0>=tau -> read h0(tau); poll f1>=tau-1 ->
//       read h1(tau-1) -> MFMA -> cells -> write h1(tau) slot tau&1 -> publish.
//   Safety: flags gate on FULL step completion (reads precede publish), so
//   slot overwrite is provably after all readers are done. Deadlock-free by
//   induction (min-progress wave's conditions always satisfied; flags init -1).
//   Structure/math otherwise = R9: 12 waves (4 L0 x 16 units, 8 L1 x 8 units),
//   2-term weight-split GEMM, single-bf16 h, exp2-folded scales, packed cells.

#define TT 512
#define HH 64
#define NB 16
#define XP 516

typedef __bf16 bf16_t;
typedef bf16_t bf16x8 __attribute__((ext_vector_type(8)));
typedef float  f32x4  __attribute__((ext_vector_type(4)));
typedef float  f32x2  __attribute__((ext_vector_type(2)));

#define MFMA(A, B, C) __builtin_amdgcn_mfma_f32_16x16x32_bf16((A), (B), (C), 0, 0, 0)
#define RCPF(x) __builtin_amdgcn_rcpf(x)

#if __has_builtin(__builtin_amdgcn_exp2f)
#define EXP2F(x) __builtin_amdgcn_exp2f(x)
#else
__device__ __forceinline__ float EXP2F(float x) {
    float r;
    asm volatile("v_exp_f32 %0, %1" : "=v"(r) : "v"(x));
    return r;
}
#endif

#define SC_IFO (-1.4426950408889634f)   // -log2(e)
#define SC_G   ( 2.8853900817779268f)   // +2*log2(e)

__device__ __forceinline__ unsigned short f32_to_bf16_rne(float f) {
    unsigned int u = __builtin_bit_cast(unsigned int, f);
    unsigned int r = u + 0x7fffu + ((u >> 16) & 1u);
    return (unsigned short)(r >> 16);
}
__device__ __forceinline__ float bf16bits_to_f32(unsigned short s) {
    return __builtin_bit_cast(float, ((unsigned int)s) << 16);
}
__device__ __forceinline__ bf16_t bits_to_bf16(unsigned short u) {
    return __builtin_bit_cast(bf16_t, u);
}
__device__ __forceinline__ void build_frags_scaled(const float* __restrict__ p, float sc,
                                                   bf16x8& hi, bf16x8& lo) {
    const float4 a = *(const float4*)p;
    const float4 b = *(const float4*)(p + 4);
    float v[8] = {a.x, a.y, a.z, a.w, b.x, b.y, b.z, b.w};
#pragma unroll
    for (int jj = 0; jj < 8; ++jj) {
        const float s = v[jj] * sc;
        unsigned short h = f32_to_bf16_rne(s);
        float d = s - bf16bits_to_f32(h);
        hi[jj] = bits_to_bf16(h);
        lo[jj] = bits_to_bf16(f32_to_bf16_rne(d));
    }
}

__device__ __forceinline__ f32x2 exp2v(f32x2 v) {
    f32x2 r; r[0] = EXP2F(v[0]); r[1] = EXP2F(v[1]); return r;
}
__device__ __forceinline__ f32x2 rcpv(f32x2 v) {
    f32x2 r; r[0] = RCPF(v[0]); r[1] = RCPF(v[1]); return r;
}
// Two cells on PRE-SCALED gates (is,fs,os scaled -log2e; gs scaled +2log2e).
__device__ __forceinline__ f32x2 cell2(const f32x4 a0, const f32x4 a1, f32x2* c) {
    f32x2 is = {a0[0], a1[0]}, fs = {a0[1], a1[1]};
    f32x2 gs = {a0[2], a1[2]}, os = {a0[3], a1[3]};
    const f32x2 pf = exp2v(fs);
    const f32x2 fg = rcpv(1.0f + pf);
    const f32x2 pi = exp2v(is);
    const f32x2 e2 = exp2v(gs);
    const f32x2 z  = (e2 - 1.0f) * rcpv((1.0f + pi) * (1.0f + e2));
    *c = fg * (*c) + z;
    const f32x2 po  = exp2v(os);
    const f32x2 e2c = exp2v((*c) * SC_G);
    return (e2c - 1.0f) * rcpv((1.0f + po) * (1.0f + e2c));
}

__device__ __forceinline__ int imin2(int a, int b) { return a < b ? a : b; }

__global__ __launch_bounds__(768, 3)
void lstm_ff_kernel(const float* __restrict__ x,
                    const float* __restrict__ Wih0, const float* __restrict__ Whh0,
                    const float* __restrict__ bih0, const float* __restrict__ bhh0,
                    const float* __restrict__ Wih1, const float* __restrict__ Whh1,
                    const float* __restrict__ bih1, const float* __restrict__ bhh1,
                    const float* __restrict__ Wfc,  const float* __restrict__ bfc,
                    float* __restrict__ out)
{
    __shared__ float xbuf[NB][XP];                   // 33 KB
    // rings: [slot][b][64 units] bf16, chunk-XOR swizzled within a row.
    __shared__ unsigned short h0r[8][NB][64];        // 16 KB
    __shared__ unsigned short h1r[2][NB][64];        // 4 KB
    __shared__ float h1fin[HH][NB + 1];              // 4.25 KB
    __shared__ __align__(16) int f0[4];              // L0 wave progress flags
    __shared__ __align__(16) int f1[8];              // L1 wave progress flags

    const int tid  = threadIdx.x;
    const int wv   = tid >> 6;       // 0..11: 0-3 L0 waves, 4-11 L1 waves
    const int lane = tid & 63;
    const int m    = lane & 15;      // batch col (B/C frag) & A-frag row-in-tile
    const int q    = lane >> 4;      // C-frag unit_local; A/B k-quad
    const int m7   = m & 7;
    const int b0   = blockIdx.x * NB;
    const bool isL0 = (wv < 4);

    // ---- stage x (coalesced float4) ----
    for (int i = tid; i < NB * TT / 4; i += 768) {
        const int b  = i >> 7;
        const int t4 = i & 127;
        *(float4*)&xbuf[b][t4 * 4] = *(const float4*)&x[(size_t)(b0 + b) * TT + t4 * 4];
    }
    // ---- zero rings (h(-1) comes from zeroed slots) + flags ----
    for (int i = tid; i < 8 * NB * 64; i += 768) (&h0r[0][0][0])[i] = 0;
    for (int i = tid; i < 2 * NB * 64; i += 768) (&h1r[0][0][0])[i] = 0;
    if (tid < 4) f0[tid] = -1;
    if (tid < 8) f1[tid] = -1;

    // ---- per-lane read offsets (shorts within one slot = 1024) ----
    int roff[2];
#pragma unroll
    for (int kt = 0; kt < 2; ++kt)
        roff[kt] = m * 64 + (((4 * kt + q) ^ m7) * 8);

    const int gate_m = m & 3;
    const float scA  = (gate_m == 2) ? SC_G : SC_IFO;
    unsigned short* const H0 = &h0r[0][0][0];
    unsigned short* const H1 = &h1r[0][0][0];

    __syncthreads();     // the ONLY barrier before the epilogue

    if (isL0) {
        // ===== L0 waves: units [16w,16w+16) as 4 unit-major tiles, 16 MFMA =====
        const int w = wv;
        bf16x8 Ah[4][2], Al[4][2];          // [tau][kt] of Whh0 (hi/lo split)
        f32x4 bb0s[4], wx0s[4];
        int woff[4];
#pragma unroll
        for (int tau = 0; tau < 4; ++tau) {
            const int rowA = 64 * gate_m + 16 * w + 4 * tau + (m >> 2);
#pragma unroll
            for (int kt = 0; kt < 2; ++kt)
                build_frags_scaled(&Whh0[rowA * HH + kt * 32 + q * 8], scA,
                                   Ah[tau][kt], Al[tau][kt]);
#pragma unroll
            for (int r = 0; r < 4; ++r) {
                const int row = 64 * r + 16 * w + 4 * tau + q;
                const float sc = (r == 2) ? SC_G : SC_IFO;
                bb0s[tau][r] = (bih0[row] + bhh0[row]) * sc;
                wx0s[tau][r] = Wih0[row] * sc;
            }
            const int u = 16 * w + 4 * tau + q;
            woff[tau] = m * 64 + (((u >> 3) ^ m7) * 8) + (u & 7);
        }

        f32x2 cA = {0.f, 0.f}, cB = {0.f, 0.f};

#pragma unroll 1
        for (int t = 0; t < TT; ++t) {
            // ---- wait for h0(t-1) complete (all 4 L0 waves) ----
            while (true) {
                const int4 v = *(const int4*)f0;
                if (imin2(imin2(v.x, v.y), imin2(v.z, v.w)) >= t - 1) break;
                asm volatile("" ::: "memory");
                __builtin_amdgcn_s_sleep(1);
            }
            asm volatile("" ::: "memory");

            const int rs = ((t - 1) & 7) * (NB * 64);
            bf16x8 h0[2];
            h0[0] = *(const bf16x8*)(H0 + rs + roff[0]);
            h0[1] = *(const bf16x8*)(H0 + rs + roff[1]);
            const float xv = xbuf[m][t];

            f32x4 a[4];
#pragma unroll
            for (int tau = 0; tau < 4; ++tau) {
                f32x4 p;
#pragma unroll
                for (int r = 0; r < 4; ++r)
                    p[r] = __builtin_fmaf(xv, wx0s[tau][r], bb0s[tau][r]);
                f32x4 z = {0.f, 0.f, 0.f, 0.f};
                p = MFMA(Ah[tau][0], h0[0], p);
                p = MFMA(Al[tau][0], h0[0], p);
                z = MFMA(Ah[tau][1], h0[1], z);
                z = MFMA(Al[tau][1], h0[1], z);
                a[tau] = p + z;
            }

            // ---- back-pressure: h0(t-8)'s slot must be fully consumed by L1.
            //      (polled while MFMAs are in flight) ----
            while (true) {
                const int4 va = *(const int4*)f1;
                const int4 vb = *(const int4*)(f1 + 4);
                const int mn = imin2(imin2(imin2(va.x, va.y), imin2(va.z, va.w)),
                                     imin2(imin2(vb.x, vb.y), imin2(vb.z, vb.w)));
                if (mn >= t - 8) break;
                asm volatile("" ::: "memory");
                __builtin_amdgcn_s_sleep(1);
            }
            asm volatile("" ::: "memory");

            const f32x2 hv0 = cell2(a[0], a[1], &cA);
            const f32x2 hv1 = cell2(a[2], a[3], &cB);

            const int ws = (t & 7) * (NB * 64);
            H0[ws + woff[0]] = f32_to_bf16_rne(hv0[0]);
            H0[ws + woff[1]] = f32_to_bf16_rne(hv0[1]);
            H0[ws + woff[2]] = f32_to_bf16_rne(hv1[0]);
            H0[ws + woff[3]] = f32_to_bf16_rne(hv1[1]);

            asm volatile("s_waitcnt lgkmcnt(0)" ::: "memory");
            if (lane == 0) *(volatile int*)&f0[w] = t;
        }
    } else {
        // ===== L1 waves: units [8u,8u+8) as 2 unit-major tiles, 16 MFMA =====
        const int uW = wv - 4;
        bf16x8 Ah[2][4], Al[2][4];   // [tau][kt]: kt0-1 Wih1 (eats h0), kt2-3 Whh1 (eats h1)
        f32x4 bb1s[2];
        int woff[2], uu[2];
#pragma unroll
        for (int tau = 0; tau < 2; ++tau) {
            const int rowA = 64 * gate_m + 8 * uW + 4 * tau + (m >> 2);
#pragma unroll
            for (int kt = 0; kt < 2; ++kt)
                build_frags_scaled(&Wih1[rowA * HH + kt * 32 + q * 8], scA,
                                   Ah[tau][kt], Al[tau][kt]);
#pragma unroll
            for (int kt = 0; kt < 2; ++kt)
                build_frags_scaled(&Whh1[rowA * HH + kt * 32 + q * 8], scA,
                                   Ah[tau][2 + kt], Al[tau][2 + kt]);
#pragma unroll
            for (int r = 0; r < 4; ++r) {
                const int row = 64 * r + 8 * uW + 4 * tau + q;
                const float sc = (r == 2) ? SC_G : SC_IFO;
                bb1s[tau][r] = (bih1[row] + bhh1[row]) * sc;
            }
            const int u = 8 * uW + 4 * tau + q;
            uu[tau]   = u;
            woff[tau] = m * 64 + (((u >> 3) ^ m7) * 8) + (u & 7);
        }

        f32x2 c1 = {0.f, 0.f};

#pragma unroll 1
        for (int t = 0; t < TT; ++t) {
            // ---- wait for h0(t) (all 4 L0 waves) ----
            while (true) {
                const int4 v = *(const int4*)f0;
                if (imin2(imin2(v.x, v.y), imin2(v.z, v.w)) >= t) break;
                asm volatile("" ::: "memory");
                __builtin_amdgcn_s_sleep(1);
            }
            asm volatile("" ::: "memory");
            const int rs0 = (t & 7) * (NB * 64);
            bf16x8 h0[2];
            h0[0] = *(const bf16x8*)(H0 + rs0 + roff[0]);
            h0[1] = *(const bf16x8*)(H0 + rs0 + roff[1]);

            // ---- wait for h1(t-1) (all 8 L1 waves) ----
            while (true) {
                const int4 va = *(const int4*)f1;
                const int4 vb = *(const int4*)(f1 + 4);
                const int mn = imin2(imin2(imin2(va.x, va.y), imin2(va.z, va.w)),
                                     imin2(imin2(vb.x, vb.y), imin2(vb.z, vb.w)));
                if (mn >= t - 1) break;
                asm volatile("" ::: "memory");
                __builtin_amdgcn_s_sleep(1);
            }
            asm volatile("" ::: "memory");
            const int rs1 = ((t - 1) & 1) * (NB * 64);
            bf16x8 h1[2];
            h1[0] = *(const bf16x8*)(H1 + rs1 + roff[0]);
            h1[1] = *(const bf16x8*)(H1 + rs1 + roff[1]);

            f32x4 a[2];
#pragma unroll
            for (int tau = 0; tau < 2; ++tau) {
                f32x4 p = bb1s[tau];
                f32x4 s = {0.f, 0.f, 0.f, 0.f};
                p = MFMA(Ah[tau][0], h0[0], p);        // Wih1 . h0(t)
                p = MFMA(Al[tau][0], h0[0], p);
                p = MFMA(Ah[tau][1], h0[1], p);
                p = MFMA(Al[tau][1], h0[1], p);
                s = MFMA(Ah[tau][2], h1[0], s);        // Whh1 . h1(t-1)
                s = MFMA(Al[tau][2], h1[0], s);
                s = MFMA(Ah[tau][3], h1[1], s);
                s = MFMA(Al[tau][3], h1[1], s);
                a[tau] = p + s;
            }

            const f32x2 hv = cell2(a[0], a[1], &c1);
            if (t == TT - 1) {                  // exact fp32 h1(T-1) for FC
                h1fin[uu[0]][m] = hv[0];
                h1fin[uu[1]][m] = hv[1];
            }
            const int ws = (t & 1) * (NB * 64);
            H1[ws + woff[0]] = f32_to_bf16_rne(hv[0]);
            H1[ws + woff[1]] = f32_to_bf16_rne(hv[1]);

            asm volatile("s_waitcnt lgkmcnt(0)" ::: "memory");
            if (lane == 0) *(volatile int*)&f1[uW] = t;
        }
    }

    __syncthreads();

    // ---- FC epilogue: out[b] = h1(T-1)[b] . Wfc + bfc ----
    if (tid < NB) {
        float sacc = bfc[0];
#pragma unroll
        for (int u = 0; u < HH; ++u) sacc = fmaf(h1fin[u][tid], Wfc[u], sacc);
        out[b0 + tid] = sacc;
    }
}

extern "C" void kernel_launch(void* const* d_in, const int* in_sizes, int n_in,
                              void* d_out, int out_size, void* d_ws, size_t ws_size,
                              hipStream_t stream) {
    const float* x    = (const float*)d_in[0];
    const float* Wih0 = (const float*)d_in[1];
    const float* Whh0 = (const float*)d_in[2];
    const float* bih0 = (const float*)d_in[3];
    const float* bhh0 = (const float*)d_in[4];
    const float* Wih1 = (const float*)d_in[5];
    const float* Whh1 = (const float*)d_in[6];
    const float* bih1 = (const float*)d_in[7];
    const float* bhh1 = (const float*)d_in[8];
    const float* Wfc  = (const float*)d_in[9];
    const float* bfc  = (const float*)d_in[10];

    lstm_ff_kernel<<<dim3(4096 / NB), dim3(768), 0, stream>>>(
        x, Wih0, Whh0, bih0, bhh0, Wih1, Whh1, bih1, bhh1, Wfc, bfc, (float*)d_out);
}